// Round 4
// baseline (1283.925 us; speedup 1.0000x reference)
//
#include <hip/hip_runtime.h>
#include <math.h>

#define NNODES 262144      // B*N
#define NEDGE  2097152     // NNODES*DEG
#define NB     256         // graphs
#define NPG    1024        // nodes per graph
#define EPG    8192        // edges per graph
#define DF     128         // feature dim

typedef unsigned short u16;
typedef unsigned int   u32;
typedef __attribute__((ext_vector_type(8))) short  short8;   // 8 x bf16 (4 VGPRs)
typedef __attribute__((ext_vector_type(4))) float  floatx4;  // MFMA accumulator

static constexpr int K1 = 820, K2 = 656, K3 = 525;

// ---- bf16 helpers (manual, RTNE) ----
__device__ inline float bflo(u32 u) { union { u32 i; float f; } c; c.i = u << 16;          return c.f; }
__device__ inline float bfhi(u32 u) { union { u32 i; float f; } c; c.i = u & 0xffff0000u;  return c.f; }
__device__ inline u32   f2bf(float f) {
  union { float f; u32 i; } c; c.f = f;
  const u32 r = c.i + 0x7fffu + ((c.i >> 16) & 1u);
  return r >> 16;
}
__device__ inline void acc8(float* b, uint4 v) {
  b[0] += bflo(v.x); b[1] += bfhi(v.x);
  b[2] += bflo(v.y); b[3] += bfhi(v.y);
  b[4] += bflo(v.z); b[5] += bfhi(v.z);
  b[6] += bflo(v.w); b[7] += bfhi(v.w);
}

// ---------------- CSR build (1024 thr): counting sort by dst + deg/keep init ----
__global__ __launch_bounds__(1024) void build_csr_k(
    const int* __restrict__ ei, int* __restrict__ csr_src,
    int* __restrict__ row_off, int* __restrict__ row_cnt,
    float* __restrict__ degf, float* __restrict__ keep)
{
  __shared__ int cnt[NPG];
  __shared__ int roff[NPG];
  __shared__ int wsum[NPG];
  const int b = blockIdx.x, t = threadIdx.x;   // t in 0..1023
  const int* src = ei;
  const int* dst = ei + NEDGE;
  const int e0 = b * EPG;
  cnt[t] = 0;
  __syncthreads();
  for (int e = t; e < EPG; e += 1024) atomicAdd(&cnt[dst[e0 + e] & (NPG - 1)], 1);
  __syncthreads();
  const int v = cnt[t];
  wsum[t] = v;
  __syncthreads();
  for (int off = 1; off < NPG; off <<= 1) {
    const int u = (t >= off) ? wsum[t - off] : 0;
    __syncthreads();
    wsum[t] += u;
    __syncthreads();
  }
  const int base = wsum[t] - v;    // exclusive prefix
  roff[t] = base;
  const int n = b * NPG + t;
  row_off[n] = base;
  row_cnt[n] = v;
  degf[n]    = (float)v;           // layer-1 deg = full in-degree
  keep[n]    = 1.0f;
  __syncthreads();
  for (int e = t; e < EPG; e += 1024) {
    const int dl = dst[e0 + e] & (NPG - 1);
    const int pos = atomicAdd(&roff[dl], 1);
    csr_src[e0 + pos] = src[e0 + e];   // store GLOBAL src node id
  }
}

// ---------------- Embedding gather (f32 -> bf16 scaled-features buffer) ---------
__global__ __launch_bounds__(256) void gather_k(
    const int* __restrict__ x_ids, const float* __restrict__ emb,
    u16* __restrict__ xs)
{
  const int gid = blockIdx.x * 256 + threadIdx.x;  // NNODES*16 threads
  const int n = gid >> 4, c = gid & 15;
  const int id = x_ids[n];
  const float4 v0 = *(const float4*)(emb + (size_t)id * DF + c * 8);
  const float4 v1 = *(const float4*)(emb + (size_t)id * DF + c * 8 + 4);
  uint4 pk;
  pk.x = f2bf(v0.x) | (f2bf(v0.y) << 16);
  pk.y = f2bf(v0.z) | (f2bf(v0.w) << 16);
  pk.z = f2bf(v1.x) | (f2bf(v1.y) << 16);
  pk.w = f2bf(v1.z) | (f2bf(v1.w) << 16);
  *(uint4*)(xs + (size_t)n * DF + c * 8) = pk;
}

// ---------------- Weight pre-transpose+convert: wT[l][n][k] (bf16, K=256) --------
__global__ __launch_bounds__(256) void wcvt_k(
    const float* __restrict__ Wl1, const float* __restrict__ Wr1,
    const float* __restrict__ Wl2, const float* __restrict__ Wr2,
    const float* __restrict__ Wl3, const float* __restrict__ Wr3,
    u16* __restrict__ wT)
{
  const int l = blockIdx.x >> 7, n = blockIdx.x & 127, k = threadIdx.x;
  const float* Wl = (l == 0) ? Wl1 : (l == 1) ? Wl2 : Wl3;
  const float* Wr = (l == 0) ? Wr1 : (l == 1) ? Wr2 : Wr3;
  const float v = (k < 128) ? Wl[k * 128 + n] : Wr[(k - 128) * 128 + n];
  wT[(size_t)l * 32768 + n * 256 + k] = (u16)f2bf(v);
}

// ---------------- Fused SAGE: CSR sum-aggregate (pre-scaled xs) + MFMA GEMM -----
// out = [agg | xs] @ [Wl ; Wr] + bl, relu, raw score. agg = (sum xs[src])/max(deg,1).
// block = 256 thr (4 waves), tile = 64 nodes x 128 cols, K=256.
__global__ __launch_bounds__(256) void sage_k(
    const u16* __restrict__ xs, const float* __restrict__ deg,
    const int* __restrict__ csr_src, const int* __restrict__ row_off,
    const int* __restrict__ row_cnt,
    const u16* __restrict__ wT, const float* __restrict__ bl,
    const float* __restrict__ p,
    u16* __restrict__ xnh, float* __restrict__ score)
{
  // row stride 136 u16 = 272 B: MFMA-phase ds_read_b128 conflicts are <=2-way (free)
  __shared__ u16 a_t[64 * 136];    // 17408 B total LDS
  const int tid = threadIdx.x;
  const int bi  = blockIdx.x;
  const int g   = (bi & 7) + 8 * ((bi >> 3) >> 4);   // XCD swizzle
  const int t16 = (bi >> 3) & 15;
  const int n0  = g * NPG + t16 * 64;

  // ---- Phase A: sum-aggregate (f32 regs; xs already fac-scaled) ----
  const int nl = tid >> 2, q = tid & 3;      // node-local 0..63, feat-quarter 0..3
  float bacc[32];
#pragma unroll
  for (int u = 0; u < 32; ++u) bacc[u] = 0.0f;
  {
    const int n   = n0 + nl;
    const int cnt = row_cnt[n];
    const int* ep = csr_src + g * EPG + row_off[n];
    const u16* xq = xs + q * 32;
    int e = 0;
    for (; e + 2 <= cnt; e += 2) {           // unroll-2: 8 indep 16B loads in flight
      const int s0 = ep[e], s1 = ep[e + 1];
      const uint4* r0 = (const uint4*)(xq + (size_t)s0 * DF);
      const uint4* r1 = (const uint4*)(xq + (size_t)s1 * DF);
      const uint4 A0 = r0[0], A1 = r0[1], A2 = r0[2], A3 = r0[3];
      const uint4 B0 = r1[0], B1 = r1[1], B2 = r1[2], B3 = r1[3];
      acc8(bacc + 0, A0); acc8(bacc + 8, A1); acc8(bacc + 16, A2); acc8(bacc + 24, A3);
      acc8(bacc + 0, B0); acc8(bacc + 8, B1); acc8(bacc + 16, B2); acc8(bacc + 24, B3);
    }
    if (e < cnt) {
      const int s0 = ep[e];
      const uint4* r0 = (const uint4*)(xq + (size_t)s0 * DF);
      const uint4 A0 = r0[0], A1 = r0[1], A2 = r0[2], A3 = r0[3];
      acc8(bacc + 0, A0); acc8(bacc + 8, A1); acc8(bacc + 16, A2); acc8(bacc + 24, A3);
    }
    const float inv = 1.0f / fmaxf(deg[n], 1.0f);
#pragma unroll
    for (int u = 0; u < 32; ++u) bacc[u] *= inv;
  }

  // ---- dump agg tile (bf16) ----
  {
    u16* ar = &a_t[nl * 136 + q * 32];
#pragma unroll
    for (int i = 0; i < 4; ++i) {
      uint4 o;
      o.x = f2bf(bacc[i*8+0]) | (f2bf(bacc[i*8+1]) << 16);
      o.y = f2bf(bacc[i*8+2]) | (f2bf(bacc[i*8+3]) << 16);
      o.z = f2bf(bacc[i*8+4]) | (f2bf(bacc[i*8+5]) << 16);
      o.w = f2bf(bacc[i*8+6]) | (f2bf(bacc[i*8+7]) << 16);
      *(uint4*)(ar + i * 8) = o;
    }
  }
  __syncthreads();

  // ---- MFMA GEMM: wave wv -> rows m0..m0+15, all 128 cols, K=256 ----
  const int wv = tid >> 6, lane = tid & 63;
  const int lr = lane & 15, quad = lane >> 4;
  const int m0 = wv * 16;
  short8 af[8];
#pragma unroll
  for (int ks = 0; ks < 4; ++ks)             // agg half from LDS
    af[ks] = *(const short8*)(a_t + (m0 + lr) * 136 + ks * 32 + quad * 8);
#pragma unroll
  for (int ks = 0; ks < 4; ++ks)             // x half direct from global xs
    af[4 + ks] = *(const short8*)(xs + (size_t)(n0 + m0 + lr) * DF + ks * 32 + quad * 8);
  floatx4 acc[8];
#pragma unroll
  for (int ct = 0; ct < 8; ++ct) acc[ct] = (floatx4){0.f, 0.f, 0.f, 0.f};
#pragma unroll
  for (int ct = 0; ct < 8; ++ct) {
    const u16* wrow = wT + (ct * 16 + lr) * 256 + quad * 8;
#pragma unroll
    for (int ks = 0; ks < 8; ++ks) {
      const short8 bf = *(const short8*)(wrow + ks * 32);
      acc[ct] = __builtin_amdgcn_mfma_f32_16x16x32_bf16(af[ks], bf, acc[ct], 0, 0, 0);
    }
  }
  __syncthreads();

  // ---- epilogue: bias+relu, raw score, bf16 pack via LDS, coalesced store ----
  float si[4] = {0.f, 0.f, 0.f, 0.f};
#pragma unroll
  for (int ct = 0; ct < 8; ++ct) {
    const int n = ct * 16 + lr;
    const float bn = bl[n], pn = p[n];
#pragma unroll
    for (int r = 0; r < 4; ++r) {
      const float v = fmaxf(acc[ct][r] + bn, 0.0f);
      si[r] += v * pn;
      a_t[(m0 + quad * 4 + r) * 136 + n] = (u16)f2bf(v);
    }
  }
#pragma unroll
  for (int r = 0; r < 4; ++r) {
    float s = si[r];
#pragma unroll
    for (int off = 1; off < 16; off <<= 1) s += __shfl_xor(s, off, 16);
    if (lr == 0) score[n0 + m0 + quad * 4 + r] = s;
  }
  __syncthreads();
  {
    const int row = tid >> 2, ch = tid & 3;
#pragma unroll
    for (int i = 0; i < 4; ++i) {
      const uint4 vv = *(const uint4*)(&a_t[row * 136 + (ch * 4 + i) * 8]);
      *(uint4*)(xnh + (size_t)(n0 + row) * DF + (ch * 4 + i) * 8) = vv;
    }
  }
}

// ---- Fused post-layer: top-k rank + next-deg + scale-write xs + readout --------
// One block per graph. keep[] global carries prev-active mask between layers.
__global__ __launch_bounds__(256) void post_k(
    const float* __restrict__ score, const float* __restrict__ p,
    const int* __restrict__ csr_src, const int* __restrict__ row_off,
    const int* __restrict__ row_cnt,
    const u16* __restrict__ xn, u16* __restrict__ xs,
    float* __restrict__ keep, float* __restrict__ degN,
    float* __restrict__ xl, int K, int next)
{
  __shared__ float s_lds[NPG];
  __shared__ float fac_l[NPG];
  __shared__ float kfl[NPG];
  __shared__ float mxA[256], mxB[256], smA[256], smB[256];
  const int b = blockIdx.x, t = threadIdx.x;
  float ssq = 0.0f;
  for (int d = 0; d < DF; ++d) ssq += p[d] * p[d];
  const float inv_pn = 1.0f / sqrtf(ssq);
  const float NEG = -__builtin_huge_valf();
  for (int i = t; i < NPG; i += 256) {
    const int n = b * NPG + i;
    s_lds[i] = (keep[n] > 0.5f) ? score[n] : NEG;
  }
  __syncthreads();
  // exact argsort-rank semantics: rank = #{s_j > s_i} + #{s_j == s_i, j < i}
  float si[4]; int rk[4] = {0, 0, 0, 0};
#pragma unroll
  for (int ii = 0; ii < 4; ++ii) si[ii] = s_lds[t + 256 * ii];
  for (int j = 0; j < NPG; ++j) {
    const float sj = s_lds[j];
#pragma unroll
    for (int ii = 0; ii < 4; ++ii) {
      const int idx = t + 256 * ii;
      rk[ii] += (sj > si[ii]) || ((sj == si[ii]) && (j < idx));
    }
  }
#pragma unroll
  for (int ii = 0; ii < 4; ++ii) {
    const int i = t + 256 * ii;
    const bool kp = rk[ii] < K;   // implies previously-active (inactive = -inf)
    keep[b * NPG + i] = kp ? 1.0f : 0.0f;
    kfl[i]   = kp ? 1.0f : 0.0f;
    fac_l[i] = kp ? tanhf(si[ii] * inv_pn) : 0.0f;
  }
  __syncthreads();
  // deg for next layer: whole-graph keep is in LDS -> pure LDS gather
  if (next) {
#pragma unroll
    for (int ii = 0; ii < 4; ++ii) {
      const int i = t + 256 * ii;
      const int n = b * NPG + i;
      const int cnt = row_cnt[n];
      const int* ep = csr_src + b * EPG + row_off[n];
      float dsum = 0.0f;
      for (int e = 0; e < cnt; ++e) dsum += kfl[ep[e] & (NPG - 1)];
      degN[n] = dsum;
    }
  }
  // scale-write xs (layers 1,2) + masked max/mean readout
  const int d = t & 63, rq = t >> 6;
  float mx0 = NEG, mx1 = NEG, sm0 = 0.0f, sm1 = 0.0f;
  for (int i = rq; i < NPG; i += 4) {
    const size_t base = ((size_t)(b * NPG + i)) * DF + d * 2;
    const u32 u = *(const u32*)(xn + base);
    const float f = fac_l[i];
    const float v0 = bflo(u) * f, v1 = bfhi(u) * f;
    if (next) *(u32*)(xs + base) = f2bf(v0) | (f2bf(v1) << 16);
    if (kfl[i] > 0.5f) {
      mx0 = fmaxf(mx0, v0); mx1 = fmaxf(mx1, v1);
      sm0 += v0; sm1 += v1;
    }
  }
  mxA[t] = mx0; mxB[t] = mx1; smA[t] = sm0; smB[t] = sm1;
  __syncthreads();
  if (t < 64) {
    float m0 = mxA[t], m1 = mxB[t], s0 = smA[t], s1 = smB[t];
#pragma unroll
    for (int qq = 1; qq < 4; ++qq) {
      m0 = fmaxf(m0, mxA[qq * 64 + t]); m1 = fmaxf(m1, mxB[qq * 64 + t]);
      s0 += smA[qq * 64 + t];           s1 += smB[qq * 64 + t];
    }
    const float invK = 1.0f / (float)K;
    float* o = xl + (size_t)b * 256;
    o[2 * t]           = m0;
    o[2 * t + 1]       = m1;
    o[128 + 2 * t]     = s0 * invK;    // mean (kept count == K exactly)
    o[128 + 2 * t + 1] = s1 * invK;
  }
}

// ---------------- Final MLP head, one block per graph ----------------
__global__ __launch_bounds__(256) void mlp_k(
    const float* __restrict__ xl,
    const float* __restrict__ W1, const float* __restrict__ b1,
    const float* __restrict__ W2, const float* __restrict__ b2,
    const float* __restrict__ W3, const float* __restrict__ b3,
    float* __restrict__ out)
{
  __shared__ float h0[256];
  __shared__ float h1[128];
  __shared__ float h2[64];
  const int b = blockIdx.x, t = threadIdx.x;
  h0[t] = xl[(size_t)b * 256 + t]
        + xl[(size_t)NB * 256 + (size_t)b * 256 + t]
        + xl[(size_t)2 * NB * 256 + (size_t)b * 256 + t];
  __syncthreads();
  if (t < 128) {
    float a = b1[t];
    for (int k = 0; k < 256; ++k) a += h0[k] * W1[k * 128 + t];
    h1[t] = fmaxf(a, 0.0f);
  }
  __syncthreads();
  if (t < 64) {
    float a = b2[t];
    for (int k = 0; k < 128; ++k) a += h1[k] * W2[k * 64 + t];
    h2[t] = fmaxf(a, 0.0f);
  }
  __syncthreads();
  if (t < 64) {
    float vv = h2[t] * W3[t];
#pragma unroll
    for (int off = 32; off > 0; off >>= 1) vv += __shfl_xor(vv, off, 64);
    if (t == 0) out[b] = 1.0f / (1.0f + expf(-(vv + b3[0])));
  }
}

extern "C" void kernel_launch(void* const* d_in, const int* in_sizes, int n_in,
                              void* d_out, int out_size, void* d_ws, size_t ws_size,
                              hipStream_t stream)
{
  const int*   x_ids = (const int*)d_in[0];
  const int*   ei    = (const int*)d_in[1];
  const float* emb   = (const float*)d_in[3];
  const float* Wl[3]  = {(const float*)d_in[4],  (const float*)d_in[8],  (const float*)d_in[12]};
  const float* blv[3] = {(const float*)d_in[5],  (const float*)d_in[9],  (const float*)d_in[13]};
  const float* Wr[3]  = {(const float*)d_in[6],  (const float*)d_in[10], (const float*)d_in[14]};
  const float* pv[3]  = {(const float*)d_in[7],  (const float*)d_in[11], (const float*)d_in[15]};
  const float* W1 = (const float*)d_in[16]; const float* b1 = (const float*)d_in[17];
  const float* W2 = (const float*)d_in[18]; const float* b2 = (const float*)d_in[19];
  const float* W3 = (const float*)d_in[20]; const float* b3 = (const float*)d_in[21];

  char* ws = (char*)d_ws;
  size_t off = 0;
  auto alloc = [&](size_t bytes) -> void* {
    void* ptr = ws + off; off += (bytes + 255) & ~(size_t)255; return ptr;
  };
  u16*   xsb   = (u16*)  alloc((size_t)NNODES * DF * 2);   // scaled features (sage input)
  u16*   xnb   = (u16*)  alloc((size_t)NNODES * DF * 2);   // sage output (unscaled)
  float* score = (float*)alloc((size_t)NNODES * 4);
  float* keep  = (float*)alloc((size_t)NNODES * 4);
  float* degf  = (float*)alloc((size_t)NNODES * 4);
  int*   csr   = (int*)  alloc((size_t)NEDGE * 4);
  int*   roff  = (int*)  alloc((size_t)NNODES * 4);
  int*   rcnt  = (int*)  alloc((size_t)NNODES * 4);
  u16*   wT    = (u16*)  alloc((size_t)3 * 128 * 256 * 2);
  float* xl    = (float*)alloc((size_t)3 * NB * 256 * 4);
  (void)in_sizes; (void)n_in; (void)out_size;
  if (off > ws_size) return;   // graceful fail instead of OOB fault

  wcvt_k<<<384, 256, 0, stream>>>(Wl[0], Wr[0], Wl[1], Wr[1], Wl[2], Wr[2], wT);
  build_csr_k<<<NB, 1024, 0, stream>>>(ei, csr, roff, rcnt, degf, keep);
  gather_k<<<NNODES * 16 / 256, 256, 0, stream>>>(x_ids, emb, xsb);
  const int Ks[3] = {K1, K2, K3};
  for (int l = 0; l < 3; ++l) {
    sage_k<<<NNODES / 64, 256, 0, stream>>>(xsb, degf, csr, roff, rcnt,
                                            wT + (size_t)l * 32768, blv[l], pv[l],
                                            xnb, score);
    post_k<<<NB, 256, 0, stream>>>(score, pv[l], csr, roff, rcnt,
                                   xnb, xsb, keep, degf,
                                   xl + (size_t)l * NB * 256, Ks[l], l < 2 ? 1 : 0);
  }
  mlp_k<<<NB, 256, 0, stream>>>(xl, W1, b1, W2, b2, W3, b3, (float*)d_out);
}

// Round 5
// 963.250 us; speedup vs baseline: 1.3329x; 1.3329x over previous
//
#include <hip/hip_runtime.h>
#include <math.h>

#define NNODES 262144      // B*N
#define NEDGE  2097152     // NNODES*DEG
#define NB     256         // graphs
#define NPG    1024        // nodes per graph
#define EPG    8192        // edges per graph
#define DF     128         // feature dim

typedef unsigned short u16;
typedef unsigned int   u32;
typedef __attribute__((ext_vector_type(8))) short  short8;   // 8 x bf16 (4 VGPRs)
typedef __attribute__((ext_vector_type(4))) float  floatx4;  // MFMA accumulator

static constexpr int K1 = 820, K2 = 656, K3 = 525;

// ---- bf16 helpers (manual, RTNE) ----
__device__ inline float bflo(u32 u) { union { u32 i; float f; } c; c.i = u << 16;          return c.f; }
__device__ inline float bfhi(u32 u) { union { u32 i; float f; } c; c.i = u & 0xffff0000u;  return c.f; }
__device__ inline u32   f2bf(float f) {
  union { float f; u32 i; } c; c.f = f;
  const u32 r = c.i + 0x7fffu + ((c.i >> 16) & 1u);
  return r >> 16;
}

// ---------------- CSR build (1024 thr): counting sort by dst + deg/keep init ----
__global__ __launch_bounds__(1024) void build_csr_k(
    const int* __restrict__ ei, int* __restrict__ csr_src,
    int* __restrict__ row_off, int* __restrict__ row_cnt,
    float* __restrict__ degf, float* __restrict__ keep)
{
  __shared__ int cnt[NPG];
  __shared__ int roff[NPG];
  __shared__ int wsum[NPG];
  const int b = blockIdx.x, t = threadIdx.x;   // t in 0..1023
  const int* src = ei;
  const int* dst = ei + NEDGE;
  const int e0 = b * EPG;
  cnt[t] = 0;
  __syncthreads();
  for (int e = t; e < EPG; e += 1024) atomicAdd(&cnt[dst[e0 + e] & (NPG - 1)], 1);
  __syncthreads();
  const int v = cnt[t];
  wsum[t] = v;
  __syncthreads();
  for (int off = 1; off < NPG; off <<= 1) {
    const int u = (t >= off) ? wsum[t - off] : 0;
    __syncthreads();
    wsum[t] += u;
    __syncthreads();
  }
  const int base = wsum[t] - v;    // exclusive prefix
  roff[t] = base;
  const int n = b * NPG + t;
  row_off[n] = base;
  row_cnt[n] = v;
  degf[n]    = (float)v;           // layer-1 deg = full in-degree
  keep[n]    = 1.0f;
  __syncthreads();
  for (int e = t; e < EPG; e += 1024) {
    const int dl = dst[e0 + e] & (NPG - 1);
    const int pos = atomicAdd(&roff[dl], 1);
    csr_src[e0 + pos] = src[e0 + e];   // store GLOBAL src node id
  }
}

// ---------------- Embedding gather (f32 -> bf16 scaled-features buffer) ---------
__global__ __launch_bounds__(256) void gather_k(
    const int* __restrict__ x_ids, const float* __restrict__ emb,
    u16* __restrict__ xs)
{
  const int gid = blockIdx.x * 256 + threadIdx.x;  // NNODES*16 threads
  const int n = gid >> 4, c = gid & 15;
  const int id = x_ids[n];
  const float4 v0 = *(const float4*)(emb + (size_t)id * DF + c * 8);
  const float4 v1 = *(const float4*)(emb + (size_t)id * DF + c * 8 + 4);
  uint4 pk;
  pk.x = f2bf(v0.x) | (f2bf(v0.y) << 16);
  pk.y = f2bf(v0.z) | (f2bf(v0.w) << 16);
  pk.z = f2bf(v1.x) | (f2bf(v1.y) << 16);
  pk.w = f2bf(v1.z) | (f2bf(v1.w) << 16);
  *(uint4*)(xs + (size_t)n * DF + c * 8) = pk;
}

// ---- Weight convert into SWIZZLED fragment order -------------------------------
// wF[l][f=ct*8+ks][lane][j] = wT[n=ct*16+(lane&15)][k=ks*32+(lane>>4)*8+j]
// where wT[n][k] = k<128 ? Wl[k][n] : Wr[k-128][n].  One wave per (l,f).
__global__ __launch_bounds__(64) void wcvt_k(
    const float* __restrict__ Wl1, const float* __restrict__ Wr1,
    const float* __restrict__ Wl2, const float* __restrict__ Wr2,
    const float* __restrict__ Wl3, const float* __restrict__ Wr3,
    u16* __restrict__ wF)
{
  const int f = blockIdx.x & 63, l = blockIdx.x >> 6;
  const int lane = threadIdx.x;
  const int ct = f >> 3, ks = f & 7;
  const int n = ct * 16 + (lane & 15);
  const int k0 = ks * 32 + (lane >> 4) * 8;
  const float* Wl = (l == 0) ? Wl1 : (l == 1) ? Wl2 : Wl3;
  const float* Wr = (l == 0) ? Wr1 : (l == 1) ? Wr2 : Wr3;
  u16 o[8];
#pragma unroll
  for (int j = 0; j < 8; ++j) {
    const int k = k0 + j;
    const float v = (k < 128) ? Wl[k * 128 + n] : Wr[(k - 128) * 128 + n];
    o[j] = (u16)f2bf(v);
  }
  uint4 pk;
  pk.x = (u32)o[0] | ((u32)o[1] << 16);
  pk.y = (u32)o[2] | ((u32)o[3] << 16);
  pk.z = (u32)o[4] | ((u32)o[5] << 16);
  pk.w = (u32)o[6] | ((u32)o[7] << 16);
  *(uint4*)(wF + (((size_t)l * 64 + f) * 64 + lane) * 8) = pk;
}

// ---- Aggregation via LDS: block = (graph, 8-feat chunk) ------------------------
// Stage graph's xs chunk as f32 LDS[1024][9] (stride 9 -> uniform banks), then
// each thread CSR-walks 4 nodes reading neighbors from LDS. Writes bf16 agg.
__global__ __launch_bounds__(256) void agg_k(
    const u16* __restrict__ xs, const float* __restrict__ deg,
    const int* __restrict__ csr_src, const int* __restrict__ row_off,
    const int* __restrict__ row_cnt,
    u16* __restrict__ aggx)
{
  __shared__ float xsl[NPG * 9];     // 36864 B
  const int t = threadIdx.x;
  const int bi = blockIdx.x;         // 4096 = 256 graphs x 16 chunks
  const int chunk = (bi >> 3) & 15;
  const int g = (bi & 7) + 8 * ((bi >> 3) >> 4);   // graph's 16 blocks share XCD
  // ---- stage chunk (bf16 -> f32) ----
#pragma unroll
  for (int r4 = 0; r4 < 4; ++r4) {
    const int row = t + r4 * 256;
    const uint4 v = *(const uint4*)(xs + (size_t)(g * NPG + row) * DF + chunk * 8);
    float* d = xsl + row * 9;
    d[0] = bflo(v.x); d[1] = bfhi(v.x);
    d[2] = bflo(v.y); d[3] = bfhi(v.y);
    d[4] = bflo(v.z); d[5] = bfhi(v.z);
    d[6] = bflo(v.w); d[7] = bfhi(v.w);
  }
  __syncthreads();
  // ---- gather-sum from LDS ----
#pragma unroll
  for (int r4 = 0; r4 < 4; ++r4) {
    const int node = t + r4 * 256;
    const int n = g * NPG + node;
    const int cnt = row_cnt[n];
    const int* ep = csr_src + g * EPG + row_off[n];
    float b[8];
#pragma unroll
    for (int j = 0; j < 8; ++j) b[j] = 0.0f;
    int e = 0;
    for (; e + 2 <= cnt; e += 2) {
      const int s0 = (ep[e] & (NPG - 1)) * 9;
      const int s1 = (ep[e + 1] & (NPG - 1)) * 9;
      const float* p0 = xsl + s0;
      const float* p1 = xsl + s1;
#pragma unroll
      for (int j = 0; j < 8; ++j) b[j] += p0[j] + p1[j];
    }
    if (e < cnt) {
      const float* p0 = xsl + (ep[e] & (NPG - 1)) * 9;
#pragma unroll
      for (int j = 0; j < 8; ++j) b[j] += p0[j];
    }
    const float inv = 1.0f / fmaxf(deg[n], 1.0f);
    uint4 pk;
    pk.x = f2bf(b[0] * inv) | (f2bf(b[1] * inv) << 16);
    pk.y = f2bf(b[2] * inv) | (f2bf(b[3] * inv) << 16);
    pk.z = f2bf(b[4] * inv) | (f2bf(b[5] * inv) << 16);
    pk.w = f2bf(b[6] * inv) | (f2bf(b[7] * inv) << 16);
    *(uint4*)(aggx + (size_t)n * DF + chunk * 8) = pk;
  }
}

// ---- MFMA GEMM: out = [agg | xs] @ W + bl, relu, raw score ---------------------
// 2048 blocks x 128 rows; wave = 32 rows (2 row-blocks share B-frags), K=256.
// aggx is read for this block's own rows only, then overwritten with xn output.
__global__ __launch_bounds__(256) void gemm_k(
    u16* __restrict__ aggx,          // in: agg rows (k 0..127); out: xn
    const u16* __restrict__ xs,      // k 128..255
    const u16* __restrict__ wF, const float* __restrict__ bl,
    const float* __restrict__ p, float* __restrict__ score)
{
  __shared__ u16 tile[128 * 136];    // 34816 B epilogue pack
  const int tid = threadIdx.x;
  const int bi = blockIdx.x;
  const int g  = (bi & 7) + 8 * ((bi >> 3) >> 3);
  const int t8 = (bi >> 3) & 7;
  const int n0 = g * NPG + t8 * 128;
  const int wv = tid >> 6, lane = tid & 63;
  const int lr = lane & 15, quad = lane >> 4;

  // A-fragments for both row-blocks (held across whole B loop)
  short8 af[2][8];
#pragma unroll
  for (int rb = 0; rb < 2; ++rb) {
    const int row = n0 + wv * 32 + rb * 16 + lr;
#pragma unroll
    for (int ks = 0; ks < 4; ++ks)
      af[rb][ks] = *(const short8*)(aggx + (size_t)row * DF + ks * 32 + quad * 8);
#pragma unroll
    for (int ks = 0; ks < 4; ++ks)
      af[rb][4 + ks] = *(const short8*)(xs + (size_t)row * DF + ks * 32 + quad * 8);
  }
  floatx4 acc[2][8];
#pragma unroll
  for (int rb = 0; rb < 2; ++rb)
#pragma unroll
    for (int ct = 0; ct < 8; ++ct) acc[rb][ct] = (floatx4){0.f, 0.f, 0.f, 0.f};
#pragma unroll
  for (int ct = 0; ct < 8; ++ct) {
#pragma unroll
    for (int ks = 0; ks < 8; ++ks) {
      const short8 bf = *(const short8*)(wF + (((ct * 8 + ks) * 64) + lane) * 8);
      acc[0][ct] = __builtin_amdgcn_mfma_f32_16x16x32_bf16(af[0][ks], bf, acc[0][ct], 0, 0, 0);
      acc[1][ct] = __builtin_amdgcn_mfma_f32_16x16x32_bf16(af[1][ks], bf, acc[1][ct], 0, 0, 0);
    }
  }
  // ---- epilogue: bias+relu, raw score (rank-invariant), pack via LDS ----
#pragma unroll
  for (int rb = 0; rb < 2; ++rb) {
    float si[4] = {0.f, 0.f, 0.f, 0.f};
#pragma unroll
    for (int ct = 0; ct < 8; ++ct) {
      const int n = ct * 16 + lr;
      const float bn = bl[n], pn = p[n];
#pragma unroll
      for (int r = 0; r < 4; ++r) {
        const float v = fmaxf(acc[rb][ct][r] + bn, 0.0f);
        si[r] += v * pn;
        tile[(wv * 32 + rb * 16 + quad * 4 + r) * 136 + n] = (u16)f2bf(v);
      }
    }
#pragma unroll
    for (int r = 0; r < 4; ++r) {
      float s = si[r];
#pragma unroll
      for (int off = 1; off < 16; off <<= 1) s += __shfl_xor(s, off, 16);
      if (lr == 0) score[n0 + wv * 32 + rb * 16 + quad * 4 + r] = s;
    }
  }
  __syncthreads();
  {
    const int row = tid >> 1, half = tid & 1;   // 128 rows, 128 B per thread
#pragma unroll
    for (int i = 0; i < 4; ++i) {
      const uint4 vv = *(const uint4*)(&tile[row * 136 + half * 64 + i * 16]);
      *(uint4*)(aggx + (size_t)(n0 + row) * DF + half * 64 + i * 16) = vv;
    }
  }
}

// ---- Per-graph top-k rank (exact argsort semantics) + edge-parallel next-deg ---
__global__ __launch_bounds__(1024) void rank_k(
    const float* __restrict__ score, const float* __restrict__ p,
    const int* __restrict__ ei,
    float* __restrict__ keep, float* __restrict__ fac,
    float* __restrict__ degN, int K, int next)
{
  __shared__ float s_lds[NPG];
  __shared__ float kfl[NPG];
  __shared__ float deg_l[NPG];
  const int b = blockIdx.x, t = threadIdx.x;
  float ssq = 0.0f;
  for (int d = 0; d < DF; ++d) ssq += p[d] * p[d];
  const float inv_pn = 1.0f / sqrtf(ssq);
  const float NEG = -__builtin_huge_valf();
  {
    const int n = b * NPG + t;
    s_lds[t] = (keep[n] > 0.5f) ? score[n] : NEG;
    deg_l[t] = 0.0f;
  }
  __syncthreads();
  const float si = s_lds[t];
  int rk = 0;
  for (int j = 0; j < NPG; ++j) {
    const float sj = s_lds[j];
    rk += (sj > si) || ((sj == si) && (j < t));
  }
  const bool kp = rk < K;          // implies previously-active (inactive = -inf)
  const int n = b * NPG + t;
  keep[n] = kp ? 1.0f : 0.0f;
  kfl[t]  = kp ? 1.0f : 0.0f;
  fac[n]  = kp ? tanhf(si * inv_pn) : 0.0f;
  __syncthreads();
  if (next) {
    const int e0 = b * EPG;
    for (int e = t; e < EPG; e += 1024) {
      const int sl = ei[e0 + e] & (NPG - 1);
      const int dl = ei[NEDGE + e0 + e] & (NPG - 1);
      atomicAdd(&deg_l[dl], kfl[sl]);
    }
    __syncthreads();
    degN[n] = deg_l[t];
  }
}

// ---- Parallel masked readout: 8 blocks/graph; also scale-writes xs -------------
__global__ __launch_bounds__(256) void readout_k(
    const u16* __restrict__ xn, const float* __restrict__ fac,
    const float* __restrict__ keep, u16* __restrict__ xs,
    float* __restrict__ xlp, int write_x)
{
  __shared__ float mxA[256], mxB[256], smA[256], smB[256];
  const int blk = blockIdx.x, b = blk >> 3, pr = blk & 7, t = threadIdx.x;
  const int d = t & 63, rq = t >> 6;
  const float NEG = -__builtin_huge_valf();
  float mx0 = NEG, mx1 = NEG, sm0 = 0.0f, sm1 = 0.0f;
  for (int j = 0; j < 32; ++j) {
    const int n = b * NPG + pr * 128 + rq + j * 4;
    const float kf = keep[n];
    const float f  = fac[n];
    const u32 u = *(const u32*)(xn + (size_t)n * DF + d * 2);
    const float v0 = bflo(u) * f, v1 = bfhi(u) * f;
    if (write_x) *(u32*)(xs + (size_t)n * DF + d * 2) = f2bf(v0) | (f2bf(v1) << 16);
    if (kf > 0.5f) {
      mx0 = fmaxf(mx0, v0); mx1 = fmaxf(mx1, v1);
      sm0 += v0; sm1 += v1;
    }
  }
  mxA[t] = mx0; mxB[t] = mx1; smA[t] = sm0; smB[t] = sm1;
  __syncthreads();
  if (t < 64) {
    float m0 = mxA[t], m1 = mxB[t], s0 = smA[t], s1 = smB[t];
#pragma unroll
    for (int qq = 1; qq < 4; ++qq) {
      m0 = fmaxf(m0, mxA[qq * 64 + t]); m1 = fmaxf(m1, mxB[qq * 64 + t]);
      s0 += smA[qq * 64 + t];           s1 += smB[qq * 64 + t];
    }
    float* o = xlp + (size_t)blk * 256;
    o[2 * t]           = m0;
    o[2 * t + 1]       = m1;
    o[128 + 2 * t]     = s0;
    o[128 + 2 * t + 1] = s1;
  }
}

// ---------------- Final MLP head, one block per graph ----------------
__global__ __launch_bounds__(256) void mlp_k(
    const float* __restrict__ xlp,
    const float* __restrict__ W1, const float* __restrict__ b1,
    const float* __restrict__ W2, const float* __restrict__ b2,
    const float* __restrict__ W3, const float* __restrict__ b3,
    float* __restrict__ out)
{
  __shared__ float h0[256];
  __shared__ float h1[128];
  __shared__ float h2[64];
  const int b = blockIdx.x, t = threadIdx.x;
  const float invK[3] = {1.0f / (float)K1, 1.0f / (float)K2, 1.0f / (float)K3};
  float v = 0.0f;
#pragma unroll
  for (int l = 0; l < 3; ++l) {
    const float* base = xlp + ((size_t)l * NB * 8 + (size_t)b * 8) * 256;
    if (t < 128) {
      float m = base[t];
#pragma unroll
      for (int pr = 1; pr < 8; ++pr) m = fmaxf(m, base[pr * 256 + t]);
      v += m;
    } else {
      float s = 0.0f;
#pragma unroll
      for (int pr = 0; pr < 8; ++pr) s += base[pr * 256 + t];
      v += s * invK[l];
    }
  }
  h0[t] = v;
  __syncthreads();
  if (t < 128) {
    float a = b1[t];
    for (int k = 0; k < 256; ++k) a += h0[k] * W1[k * 128 + t];
    h1[t] = fmaxf(a, 0.0f);
  }
  __syncthreads();
  if (t < 64) {
    float a = b2[t];
    for (int k = 0; k < 128; ++k) a += h1[k] * W2[k * 64 + t];
    h2[t] = fmaxf(a, 0.0f);
  }
  __syncthreads();
  if (t < 64) {
    float vv = h2[t] * W3[t];
#pragma unroll
    for (int off = 32; off > 0; off >>= 1) vv += __shfl_xor(vv, off, 64);
    if (t == 0) out[b] = 1.0f / (1.0f + expf(-(vv + b3[0])));
  }
}

extern "C" void kernel_launch(void* const* d_in, const int* in_sizes, int n_in,
                              void* d_out, int out_size, void* d_ws, size_t ws_size,
                              hipStream_t stream)
{
  const int*   x_ids = (const int*)d_in[0];
  const int*   ei    = (const int*)d_in[1];
  const float* emb   = (const float*)d_in[3];
  const float* Wl[3]  = {(const float*)d_in[4],  (const float*)d_in[8],  (const float*)d_in[12]};
  const float* blv[3] = {(const float*)d_in[5],  (const float*)d_in[9],  (const float*)d_in[13]};
  const float* Wr[3]  = {(const float*)d_in[6],  (const float*)d_in[10], (const float*)d_in[14]};
  const float* pv[3]  = {(const float*)d_in[7],  (const float*)d_in[11], (const float*)d_in[15]};
  const float* W1 = (const float*)d_in[16]; const float* b1 = (const float*)d_in[17];
  const float* W2 = (const float*)d_in[18]; const float* b2 = (const float*)d_in[19];
  const float* W3 = (const float*)d_in[20]; const float* b3 = (const float*)d_in[21];

  char* ws = (char*)d_ws;
  size_t off = 0;
  auto alloc = [&](size_t bytes) -> void* {
    void* ptr = ws + off; off += (bytes + 255) & ~(size_t)255; return ptr;
  };
  u16*   xs    = (u16*)  alloc((size_t)NNODES * DF * 2);   // scaled features
  u16*   aggx  = (u16*)  alloc((size_t)NNODES * DF * 2);   // agg, then xn (aliased)
  float* score = (float*)alloc((size_t)NNODES * 4);
  float* keep  = (float*)alloc((size_t)NNODES * 4);
  float* fac   = (float*)alloc((size_t)NNODES * 4);
  float* degf  = (float*)alloc((size_t)NNODES * 4);
  int*   csr   = (int*)  alloc((size_t)NEDGE * 4);
  int*   roff  = (int*)  alloc((size_t)NNODES * 4);
  int*   rcnt  = (int*)  alloc((size_t)NNODES * 4);
  u16*   wF    = (u16*)  alloc((size_t)3 * 64 * 64 * 8 * 2);
  float* xlp   = (float*)alloc((size_t)3 * NB * 8 * 256 * 4);
  (void)in_sizes; (void)n_in; (void)out_size;
  if (off > ws_size) return;   // graceful fail instead of OOB fault

  wcvt_k<<<192, 64, 0, stream>>>(Wl[0], Wr[0], Wl[1], Wr[1], Wl[2], Wr[2], wF);
  build_csr_k<<<NB, 1024, 0, stream>>>(ei, csr, roff, rcnt, degf, keep);
  gather_k<<<NNODES * 16 / 256, 256, 0, stream>>>(x_ids, emb, xs);
  const int Ks[3] = {K1, K2, K3};
  for (int l = 0; l < 3; ++l) {
    agg_k<<<4096, 256, 0, stream>>>(xs, degf, csr, roff, rcnt, aggx);
    gemm_k<<<2048, 256, 0, stream>>>(aggx, xs, wF + (size_t)l * 32768,
                                     blv[l], pv[l], score);
    rank_k<<<NB, 1024, 0, stream>>>(score, pv[l], ei, keep, fac, degf,
                                    Ks[l], l < 2 ? 1 : 0);
    readout_k<<<NB * 8, 256, 0, stream>>>(aggx, fac, keep, xs,
                                          xlp + (size_t)l * NB * 8 * 256,
                                          l < 2 ? 1 : 0);
  }
  mlp_k<<<NB, 256, 0, stream>>>(xlp, W1, b1, W2, b2, W3, b3, (float*)d_out);
}

// Round 6
// 839.136 us; speedup vs baseline: 1.5301x; 1.1479x over previous
//
#include <hip/hip_runtime.h>
#include <math.h>

#define NNODES 262144      // B*N
#define NEDGE  2097152     // NNODES*DEG
#define NB     256         // graphs
#define NPG    1024        // nodes per graph
#define EPG    8192        // edges per graph
#define DF     128         // feature dim

typedef unsigned short u16;
typedef unsigned int   u32;
typedef __attribute__((ext_vector_type(8))) short  short8;   // 8 x bf16 (4 VGPRs)
typedef __attribute__((ext_vector_type(4))) float  floatx4;  // MFMA accumulator

static constexpr int K1 = 820, K2 = 656, K3 = 525;

// ---- bf16 helpers (manual, RTNE) ----
__device__ inline float bflo(u32 u) { union { u32 i; float f; } c; c.i = u << 16;          return c.f; }
__device__ inline float bfhi(u32 u) { union { u32 i; float f; } c; c.i = u & 0xffff0000u;  return c.f; }
__device__ inline u32   f2bf(float f) {
  union { float f; u32 i; } c; c.f = f;
  const u32 r = c.i + 0x7fffu + ((c.i >> 16) & 1u);
  return r >> 16;
}
__device__ inline void acc8(float* b, uint4 v) {
  b[0] += bflo(v.x); b[1] += bfhi(v.x);
  b[2] += bflo(v.y); b[3] += bfhi(v.y);
  b[4] += bflo(v.z); b[5] += bfhi(v.z);
  b[6] += bflo(v.w); b[7] += bfhi(v.w);
}
__device__ inline uint4 pack8(const float* s, float k) {
  uint4 o;
  o.x = f2bf(s[0] * k) | (f2bf(s[1] * k) << 16);
  o.y = f2bf(s[2] * k) | (f2bf(s[3] * k) << 16);
  o.z = f2bf(s[4] * k) | (f2bf(s[5] * k) << 16);
  o.w = f2bf(s[6] * k) | (f2bf(s[7] * k) << 16);
  return o;
}

// ---------------- CSR build (1024 thr): counting sort by dst + deg/keep init ----
__global__ __launch_bounds__(1024) void build_csr_k(
    const int* __restrict__ ei, int* __restrict__ csr_src,
    int* __restrict__ row_off, int* __restrict__ row_cnt,
    float* __restrict__ degf, float* __restrict__ keep)
{
  __shared__ int cnt[NPG];
  __shared__ int roff[NPG];
  __shared__ int wsum[NPG];
  const int b = blockIdx.x, t = threadIdx.x;   // t in 0..1023
  const int* src = ei;
  const int* dst = ei + NEDGE;
  const int e0 = b * EPG;
  cnt[t] = 0;
  __syncthreads();
  for (int e = t; e < EPG; e += 1024) atomicAdd(&cnt[dst[e0 + e] & (NPG - 1)], 1);
  __syncthreads();
  const int v = cnt[t];
  wsum[t] = v;
  __syncthreads();
  for (int off = 1; off < NPG; off <<= 1) {
    const int u = (t >= off) ? wsum[t - off] : 0;
    __syncthreads();
    wsum[t] += u;
    __syncthreads();
  }
  const int base = wsum[t] - v;    // exclusive prefix
  roff[t] = base;
  const int n = b * NPG + t;
  row_off[n] = base;
  row_cnt[n] = v;
  degf[n]    = (float)v;           // layer-1 deg = full in-degree
  keep[n]    = 1.0f;
  __syncthreads();
  for (int e = t; e < EPG; e += 1024) {
    const int dl = dst[e0 + e] & (NPG - 1);
    const int pos = atomicAdd(&roff[dl], 1);
    csr_src[e0 + pos] = src[e0 + e];   // store GLOBAL src node id
  }
}

// ---------------- Embedding gather (f32 -> bf16 scaled-features buffer) ---------
__global__ __launch_bounds__(256) void gather_k(
    const int* __restrict__ x_ids, const float* __restrict__ emb,
    u16* __restrict__ xs)
{
  const int gid = blockIdx.x * 256 + threadIdx.x;  // NNODES*16 threads
  const int n = gid >> 4, c = gid & 15;
  const int id = x_ids[n];
  const float4 v0 = *(const float4*)(emb + (size_t)id * DF + c * 8);
  const float4 v1 = *(const float4*)(emb + (size_t)id * DF + c * 8 + 4);
  uint4 pk;
  pk.x = f2bf(v0.x) | (f2bf(v0.y) << 16);
  pk.y = f2bf(v0.z) | (f2bf(v0.w) << 16);
  pk.z = f2bf(v1.x) | (f2bf(v1.y) << 16);
  pk.w = f2bf(v1.z) | (f2bf(v1.w) << 16);
  *(uint4*)(xs + (size_t)n * DF + c * 8) = pk;
}

// ---- Weight convert into SWIZZLED fragment order -------------------------------
// wF[l][f=ct*8+ks][lane][j] = wT[n=ct*16+(lane&15)][k=ks*32+(lane>>4)*8+j]
// where wT[n][k] = k<128 ? Wl[k][n] : Wr[k-128][n].  One wave per (l,f).
__global__ __launch_bounds__(64) void wcvt_k(
    const float* __restrict__ Wl1, const float* __restrict__ Wr1,
    const float* __restrict__ Wl2, const float* __restrict__ Wr2,
    const float* __restrict__ Wl3, const float* __restrict__ Wr3,
    u16* __restrict__ wF)
{
  const int f = blockIdx.x & 63, l = blockIdx.x >> 6;
  const int lane = threadIdx.x;
  const int ct = f >> 3, ks = f & 7;
  const int n = ct * 16 + (lane & 15);
  const int k0 = ks * 32 + (lane >> 4) * 8;
  const float* Wl = (l == 0) ? Wl1 : (l == 1) ? Wl2 : Wl3;
  const float* Wr = (l == 0) ? Wr1 : (l == 1) ? Wr2 : Wr3;
  u16 o[8];
#pragma unroll
  for (int j = 0; j < 8; ++j) {
    const int k = k0 + j;
    const float v = (k < 128) ? Wl[k * 128 + n] : Wr[(k - 128) * 128 + n];
    o[j] = (u16)f2bf(v);
  }
  uint4 pk;
  pk.x = (u32)o[0] | ((u32)o[1] << 16);
  pk.y = (u32)o[2] | ((u32)o[3] << 16);
  pk.z = (u32)o[4] | ((u32)o[5] << 16);
  pk.w = (u32)o[6] | ((u32)o[7] << 16);
  *(uint4*)(wF + (((size_t)l * 64 + f) * 64 + lane) * 8) = pk;
}

// ---- Aggregation v2: direct L2 gather, edge-slot parallel ----------------------
// block = 32 nodes; thread = (node, 32-feat quarter, edge-slot of 2).
// Graph slice (256 KB) is XCD-L2-resident via swizzle. Small padded LDS reduce.
__global__ __launch_bounds__(256) void agg_k(
    const u16* __restrict__ xs, const float* __restrict__ deg,
    const int* __restrict__ csr_src, const int* __restrict__ row_off,
    const int* __restrict__ row_cnt,
    u16* __restrict__ aggx)
{
  __shared__ float part[256 * 33];   // 33792 B; stride 33 -> conflict-free
  const int t = threadIdx.x;
  const int bi = blockIdx.x;                 // 8192 = 256 graphs x 32 chunks
  const int g = (bi & 7) + 8 * (bi >> 8);    // graph's 32 blocks share XCD
  const int chunk = (bi >> 3) & 31;
  const int node = t >> 3, q = (t >> 1) & 3, es = t & 1;
  const int n = g * NPG + chunk * 32 + node;
  const int cnt = row_cnt[n];
  const int* ep = csr_src + g * EPG + row_off[n];
  const u16* xq = xs + q * 32;
  float b[32];
#pragma unroll
  for (int j = 0; j < 32; ++j) b[j] = 0.0f;
  int e = es;
  for (; e + 2 < cnt; e += 4) {              // 2 edges/iter -> 8 uint4 in flight
    const int s0 = ep[e], s1 = ep[e + 2];
    const uint4* r0 = (const uint4*)(xq + (size_t)s0 * DF);
    const uint4* r1 = (const uint4*)(xq + (size_t)s1 * DF);
    const uint4 A0 = r0[0], A1 = r0[1], A2 = r0[2], A3 = r0[3];
    const uint4 B0 = r1[0], B1 = r1[1], B2 = r1[2], B3 = r1[3];
    acc8(b + 0, A0); acc8(b + 8, A1); acc8(b + 16, A2); acc8(b + 24, A3);
    acc8(b + 0, B0); acc8(b + 8, B1); acc8(b + 16, B2); acc8(b + 24, B3);
  }
  if (e < cnt) {
    const int s0 = ep[e];
    const uint4* r0 = (const uint4*)(xq + (size_t)s0 * DF);
    const uint4 A0 = r0[0], A1 = r0[1], A2 = r0[2], A3 = r0[3];
    acc8(b + 0, A0); acc8(b + 8, A1); acc8(b + 16, A2); acc8(b + 24, A3);
  }
  {
    float* pp = part + t * 33;
#pragma unroll
    for (int j = 0; j < 32; ++j) pp[j] = b[j];
  }
  __syncthreads();
  if (es == 0) {
    const float* pr = part + (t + 1) * 33;
#pragma unroll
    for (int j = 0; j < 32; ++j) b[j] += pr[j];
    const float inv = 1.0f / fmaxf(deg[n], 1.0f);
    uint4* op = (uint4*)(aggx + (size_t)n * DF + q * 32);
    op[0] = pack8(b + 0,  inv);
    op[1] = pack8(b + 8,  inv);
    op[2] = pack8(b + 16, inv);
    op[3] = pack8(b + 24, inv);
  }
}

// ---- MFMA GEMM v2: no LDS, direct C-layout stores ------------------------------
// out = [agg | xs] @ W + bl, relu, raw score. 2048 blocks x 128 rows.
// ks-outer/ct-inner: only 2 A-frags live; B-frags (wF) L2-hot, coalesced 1KB/wave.
__global__ __launch_bounds__(256) void gemm_k(
    u16* __restrict__ aggx,          // in: agg rows (k 0..127); out: xn
    const u16* __restrict__ xs,      // k 128..255
    const u16* __restrict__ wF, const float* __restrict__ bl,
    const float* __restrict__ p, float* __restrict__ score)
{
  const int tid = threadIdx.x;
  const int bi = blockIdx.x;
  const int g  = (bi & 7) + 8 * (bi >> 6);
  const int t8 = (bi >> 3) & 7;
  const int n0 = g * NPG + t8 * 128;
  const int wv = tid >> 6, lane = tid & 63;
  const int lr = lane & 15, quad = lane >> 4;
  const int r0 = n0 + wv * 32 + lr;          // rb0 row; rb1 = +16

  floatx4 acc[2][8];
#pragma unroll
  for (int rb = 0; rb < 2; ++rb)
#pragma unroll
    for (int ct = 0; ct < 8; ++ct) acc[rb][ct] = (floatx4){0.f, 0.f, 0.f, 0.f};

#pragma unroll
  for (int ks = 0; ks < 8; ++ks) {
    const u16* asrc = (ks < 4) ? aggx : xs;
    const int koff = (ks & 3) * 32 + quad * 8;
    const short8 a0 = *(const short8*)(asrc + (size_t)r0 * DF + koff);
    const short8 a1 = *(const short8*)(asrc + (size_t)(r0 + 16) * DF + koff);
#pragma unroll
    for (int ct = 0; ct < 8; ++ct) {
      const short8 bf = *(const short8*)(wF + (((ct * 8 + ks) * 64) + lane) * 8);
      acc[0][ct] = __builtin_amdgcn_mfma_f32_16x16x32_bf16(a0, bf, acc[0][ct], 0, 0, 0);
      acc[1][ct] = __builtin_amdgcn_mfma_f32_16x16x32_bf16(a1, bf, acc[1][ct], 0, 0, 0);
    }
  }
  // ---- epilogue: bias+relu, raw score (rank-invariant), direct u16 stores ----
#pragma unroll
  for (int rb = 0; rb < 2; ++rb) {
    float si[4] = {0.f, 0.f, 0.f, 0.f};
#pragma unroll
    for (int ct = 0; ct < 8; ++ct) {
      const int nn = ct * 16 + lr;
      const float bn = bl[nn], pn = p[nn];
#pragma unroll
      for (int r = 0; r < 4; ++r) {
        const float v = fmaxf(acc[rb][ct][r] + bn, 0.0f);
        si[r] += v * pn;
        aggx[(size_t)(n0 + wv * 32 + rb * 16 + quad * 4 + r) * DF + nn] = (u16)f2bf(v);
      }
    }
#pragma unroll
    for (int r = 0; r < 4; ++r) {
      float s = si[r];
#pragma unroll
      for (int off = 1; off < 16; off <<= 1) s += __shfl_xor(s, off, 16);
      if (lr == 0) score[n0 + wv * 32 + rb * 16 + quad * 4 + r] = s;
    }
  }
}

// ---- Per-graph top-k rank (exact argsort semantics) + edge-parallel next-deg ---
__global__ __launch_bounds__(1024) void rank_k(
    const float* __restrict__ score, const float* __restrict__ p,
    const int* __restrict__ ei,
    float* __restrict__ keep, float* __restrict__ fac,
    float* __restrict__ degN, int K, int next)
{
  __shared__ float s_lds[NPG];
  __shared__ float kfl[NPG];
  __shared__ float deg_l[NPG];
  const int b = blockIdx.x, t = threadIdx.x;
  float ssq = 0.0f;
  for (int d = 0; d < DF; ++d) ssq += p[d] * p[d];
  const float inv_pn = 1.0f / sqrtf(ssq);
  const float NEG = -__builtin_huge_valf();
  {
    const int n = b * NPG + t;
    s_lds[t] = (keep[n] > 0.5f) ? score[n] : NEG;
    deg_l[t] = 0.0f;
  }
  __syncthreads();
  const float si = s_lds[t];
  int rk = 0;
  for (int j = 0; j < NPG; ++j) {
    const float sj = s_lds[j];
    rk += (sj > si) || ((sj == si) && (j < t));
  }
  const bool kp = rk < K;          // implies previously-active (inactive = -inf)
  const int n = b * NPG + t;
  keep[n] = kp ? 1.0f : 0.0f;
  kfl[t]  = kp ? 1.0f : 0.0f;
  fac[n]  = kp ? tanhf(si * inv_pn) : 0.0f;
  __syncthreads();
  if (next) {
    const int e0 = b * EPG;
    for (int e = t; e < EPG; e += 1024) {
      const int sl = ei[e0 + e] & (NPG - 1);
      const int dl = ei[NEDGE + e0 + e] & (NPG - 1);
      atomicAdd(&deg_l[dl], kfl[sl]);
    }
    __syncthreads();
    degN[n] = deg_l[t];
  }
}

// ---- Parallel masked readout: 8 blocks/graph; also scale-writes xs -------------
__global__ __launch_bounds__(256) void readout_k(
    const u16* __restrict__ xn, const float* __restrict__ fac,
    const float* __restrict__ keep, u16* __restrict__ xs,
    float* __restrict__ xlp, int write_x)
{
  __shared__ float mxA[256], mxB[256], smA[256], smB[256];
  const int blk = blockIdx.x, b = blk >> 3, pr = blk & 7, t = threadIdx.x;
  const int d = t & 63, rq = t >> 6;
  const float NEG = -__builtin_huge_valf();
  float mx0 = NEG, mx1 = NEG, sm0 = 0.0f, sm1 = 0.0f;
  for (int j = 0; j < 32; ++j) {
    const int n = b * NPG + pr * 128 + rq + j * 4;
    const float kf = keep[n];
    const float f  = fac[n];
    const u32 u = *(const u32*)(xn + (size_t)n * DF + d * 2);
    const float v0 = bflo(u) * f, v1 = bfhi(u) * f;
    if (write_x) *(u32*)(xs + (size_t)n * DF + d * 2) = f2bf(v0) | (f2bf(v1) << 16);
    if (kf > 0.5f) {
      mx0 = fmaxf(mx0, v0); mx1 = fmaxf(mx1, v1);
      sm0 += v0; sm1 += v1;
    }
  }
  mxA[t] = mx0; mxB[t] = mx1; smA[t] = sm0; smB[t] = sm1;
  __syncthreads();
  if (t < 64) {
    float m0 = mxA[t], m1 = mxB[t], s0 = smA[t], s1 = smB[t];
#pragma unroll
    for (int qq = 1; qq < 4; ++qq) {
      m0 = fmaxf(m0, mxA[qq * 64 + t]); m1 = fmaxf(m1, mxB[qq * 64 + t]);
      s0 += smA[qq * 64 + t];           s1 += smB[qq * 64 + t];
    }
    float* o = xlp + (size_t)blk * 256;
    o[2 * t]           = m0;
    o[2 * t + 1]       = m1;
    o[128 + 2 * t]     = s0;
    o[128 + 2 * t + 1] = s1;
  }
}

// ---------------- Final MLP head, one block per graph ----------------
__global__ __launch_bounds__(256) void mlp_k(
    const float* __restrict__ xlp,
    const float* __restrict__ W1, const float* __restrict__ b1,
    const float* __restrict__ W2, const float* __restrict__ b2,
    const float* __restrict__ W3, const float* __restrict__ b3,
    float* __restrict__ out)
{
  __shared__ float h0[256];
  __shared__ float h1[128];
  __shared__ float h2[64];
  const int b = blockIdx.x, t = threadIdx.x;
  const float invK[3] = {1.0f / (float)K1, 1.0f / (float)K2, 1.0f / (float)K3};
  float v = 0.0f;
#pragma unroll
  for (int l = 0; l < 3; ++l) {
    const float* base = xlp + ((size_t)l * NB * 8 + (size_t)b * 8) * 256;
    if (t < 128) {
      float m = base[t];
#pragma unroll
      for (int pr = 1; pr < 8; ++pr) m = fmaxf(m, base[pr * 256 + t]);
      v += m;
    } else {
      float s = 0.0f;
#pragma unroll
      for (int pr = 0; pr < 8; ++pr) s += base[pr * 256 + t];
      v += s * invK[l];
    }
  }
  h0[t] = v;
  __syncthreads();
  if (t < 128) {
    float a = b1[t];
    for (int k = 0; k < 256; ++k) a += h0[k] * W1[k * 128 + t];
    h1[t] = fmaxf(a, 0.0f);
  }
  __syncthreads();
  if (t < 64) {
    float a = b2[t];
    for (int k = 0; k < 128; ++k) a += h1[k] * W2[k * 64 + t];
    h2[t] = fmaxf(a, 0.0f);
  }
  __syncthreads();
  if (t < 64) {
    float vv = h2[t] * W3[t];
#pragma unroll
    for (int off = 32; off > 0; off >>= 1) vv += __shfl_xor(vv, off, 64);
    if (t == 0) out[b] = 1.0f / (1.0f + expf(-(vv + b3[0])));
  }
}

extern "C" void kernel_launch(void* const* d_in, const int* in_sizes, int n_in,
                              void* d_out, int out_size, void* d_ws, size_t ws_size,
                              hipStream_t stream)
{
  const int*   x_ids = (const int*)d_in[0];
  const int*   ei    = (const int*)d_in[1];
  const float* emb   = (const float*)d_in[3];
  const float* Wl[3]  = {(const float*)d_in[4],  (const float*)d_in[8],  (const float*)d_in[12]};
  const float* blv[3] = {(const float*)d_in[5],  (const float*)d_in[9],  (const float*)d_in[13]};
  const float* Wr[3]  = {(const float*)d_in[6],  (const float*)d_in[10], (const float*)d_in[14]};
  const float* pv[3]  = {(const float*)d_in[7],  (const float*)d_in[11], (const float*)d_in[15]};
  const float* W1 = (const float*)d_in[16]; const float* b1 = (const float*)d_in[17];
  const float* W2 = (const float*)d_in[18]; const float* b2 = (const float*)d_in[19];
  const float* W3 = (const float*)d_in[20]; const float* b3 = (const float*)d_in[21];

  char* ws = (char*)d_ws;
  size_t off = 0;
  auto alloc = [&](size_t bytes) -> void* {
    void* ptr = ws + off; off += (bytes + 255) & ~(size_t)255; return ptr;
  };
  u16*   xs    = (u16*)  alloc((size_t)NNODES * DF * 2);   // scaled features
  u16*   aggx  = (u16*)  alloc((size_t)NNODES * DF * 2);   // agg, then xn (aliased)
  float* score = (float*)alloc((size_t)NNODES * 4);
  float* keep  = (float*)alloc((size_t)NNODES * 4);
  float* fac   = (float*)alloc((size_t)NNODES * 4);
  float* degf  = (float*)alloc((size_t)NNODES * 4);
  int*   csr   = (int*)  alloc((size_t)NEDGE * 4);
  int*   roff  = (int*)  alloc((size_t)NNODES * 4);
  int*   rcnt  = (int*)  alloc((size_t)NNODES * 4);
  u16*   wF    = (u16*)  alloc((size_t)3 * 64 * 64 * 8 * 2);
  float* xlp   = (float*)alloc((size_t)3 * NB * 8 * 256 * 4);
  (void)in_sizes; (void)n_in; (void)out_size;
  if (off > ws_size) return;   // graceful fail instead of OOB fault

  wcvt_k<<<192, 64, 0, stream>>>(Wl[0], Wr[0], Wl[1], Wr[1], Wl[2], Wr[2], wF);
  build_csr_k<<<NB, 1024, 0, stream>>>(ei, csr, roff, rcnt, degf, keep);
  gather_k<<<NNODES * 16 / 256, 256, 0, stream>>>(x_ids, emb, xs);
  const int Ks[3] = {K1, K2, K3};
  for (int l = 0; l < 3; ++l) {
    agg_k<<<8192, 256, 0, stream>>>(xs, degf, csr, roff, rcnt, aggx);
    gemm_k<<<2048, 256, 0, stream>>>(aggx, xs, wF + (size_t)l * 32768,
                                     blv[l], pv[l], score);
    rank_k<<<NB, 1024, 0, stream>>>(score, pv[l], ei, keep, fac, degf,
                                    Ks[l], l < 2 ? 1 : 0);
    readout_k<<<NB * 8, 256, 0, stream>>>(aggx, fac, keep, xs,
                                          xlp + (size_t)l * NB * 8 * 256,
                                          l < 2 ? 1 : 0);
  }
  mlp_k<<<NB, 256, 0, stream>>>(xlp, W1, b1, W2, b2, W3, b3, (float*)d_out);
}